// Round 1
// baseline (1044.411 us; speedup 1.0000x reference)
//
#include <hip/hip_runtime.h>
#include <cstdint>

#define F_IN  128
#define F_HID 16
#define F_OUT 138

// ---------------------------------------------------------------------------
// Detect edge_index dtype: if buffer is int64 (little-endian, values < 2^31),
// every odd int32 word is the zero high-word. For int32 data, odd words are
// random node ids in [0,1e5) -> all-zero over 1024 samples has prob ~0.
// flag = 1 -> int64 (stride 2 in int32 words), 0 -> int32 (stride 1).
__global__ void k_detect(const int* __restrict__ idx, int* __restrict__ flag) {
    __shared__ int nz;
    if (threadIdx.x == 0) nz = 0;
    __syncthreads();
    for (int i = threadIdx.x; i < 1024; i += blockDim.x)
        if (idx[2 * i + 1] != 0) nz = 1;   // benign race: all writers store 1
    __syncthreads();
    if (threadIdx.x == 0) *flag = (nz == 0) ? 1 : 0;
}

// deg init: self-loop contributes 1 to every node's degree
__global__ void k_deg_init(float* __restrict__ deg, int n) {
    int i = blockIdx.x * blockDim.x + threadIdx.x;
    if (i < n) deg[i] = 1.0f;
}

__global__ void k_deg_count(const int* __restrict__ idx, const int* __restrict__ flag,
                            float* __restrict__ deg, int E) {
    const int mult = 1 + *flag;
    size_t stride = (size_t)gridDim.x * blockDim.x;
    for (size_t e = (size_t)blockIdx.x * blockDim.x + threadIdx.x; e < (size_t)E; e += stride) {
        int d = idx[((size_t)E + e) * mult];
        atomicAdd(&deg[d], 1.0f);
    }
}

__global__ void k_rsqrt(float* __restrict__ deg, int n) {
    int i = blockIdx.x * blockDim.x + threadIdx.x;
    if (i < n) deg[i] = rsqrtf(deg[i]);   // deg >= 1 always (self-loop)
}

// g1[n][j] = dinv[n] * sum_k x[n][k] * W1[k][j]; written to buf1 AND buf2
// (buf2 is the layer-1 accumulator, init = self-loop term g1[n]).
// Block = 256 threads = 16 nodes x 16 hidden feats. x rows staged in LDS.
__global__ void k_gemm1(const float* __restrict__ x, const float* __restrict__ W1,
                        const float* __restrict__ dinv,
                        float* __restrict__ buf1, float* __restrict__ buf2, int n) {
    __shared__ float w1s[F_IN * F_HID];     // 8 KB
    __shared__ float xs[16][F_IN + 4];      // pad 132: lanes' rows land on distinct banks
    int tid = threadIdx.x;
    for (int i = tid; i < F_IN * F_HID; i += 256) w1s[i] = W1[i];
    int nb = blockIdx.x * 16;
    // 16 rows x 128 floats = 512 float4 loads, coalesced
    for (int q = tid; q < 512; q += 256) {
        int r = q >> 5, k4 = q & 31;
        int g = nb + r;
        float4 v = make_float4(0.f, 0.f, 0.f, 0.f);
        if (g < n) v = ((const float4*)x)[(size_t)g * 32 + k4];
        xs[r][k4 * 4 + 0] = v.x; xs[r][k4 * 4 + 1] = v.y;
        xs[r][k4 * 4 + 2] = v.z; xs[r][k4 * 4 + 3] = v.w;
    }
    __syncthreads();
    int r = tid >> 4, j = tid & 15;
    int g = nb + r;
    if (g < n) {
        float acc = 0.f;
#pragma unroll
        for (int k = 0; k < F_IN; ++k) acc += xs[r][k] * w1s[k * F_HID + j];
        float v = acc * dinv[g];
        size_t o = (size_t)g * F_HID + j;
        buf1[o] = v;
        buf2[o] = v;
    }
}

// For each edge: acc[dst][j] += g[src][j], j = 0..15. 16 threads per edge.
__global__ void k_scatter(const int* __restrict__ idx, const int* __restrict__ flag,
                          const float* __restrict__ g, float* __restrict__ acc, int E) {
    const int mult = 1 + *flag;
    size_t gid = (size_t)blockIdx.x * blockDim.x + threadIdx.x;
    int j = (int)(gid & 15);
    size_t stride = ((size_t)gridDim.x * blockDim.x) >> 4;
    for (size_t e = gid >> 4; e < (size_t)E; e += stride) {
        int s = idx[e * mult];
        int d = idx[((size_t)E + e) * mult];
        atomicAdd(&acc[(size_t)d * F_HID + j], g[(size_t)s * F_HID + j]);
    }
}

// h2 = relu(dinv*A + b1); g2 = dinv*h2. Write g2 to buf1 and (self-loop init) buf2.
__global__ void k_apply(const float* __restrict__ b1, const float* __restrict__ dinv,
                        float* __restrict__ buf1, float* __restrict__ buf2, int n) {
    int total = n * F_HID;
    int i = blockIdx.x * blockDim.x + threadIdx.x;
    if (i < total) {
        int node = i >> 4, j = i & 15;
        float di = dinv[node];
        float v = fmaxf(di * buf2[i] + b1[j], 0.f) * di;
        buf1[i] = v;
        buf2[i] = v;
    }
}

// out[n][c] = dinv[n] * sum_j B[n][j]*W2[j][c] + b2[c]
__global__ void k_out(const float* __restrict__ B, const float* __restrict__ dinv,
                      const float* __restrict__ W2, const float* __restrict__ b2,
                      float* __restrict__ out, int n) {
    __shared__ float w2s[F_HID * F_OUT];   // 8.8 KB
    __shared__ float b2s[F_OUT];
    int tid = threadIdx.x;
    for (int i = tid; i < F_HID * F_OUT; i += 256) w2s[i] = W2[i];
    if (tid < F_OUT) b2s[tid] = b2[tid];
    __syncthreads();
    int total = n * F_OUT;
    int stride = gridDim.x * blockDim.x;
    for (int i = blockIdx.x * blockDim.x + tid; i < total; i += stride) {
        int node = i / F_OUT, c = i - node * F_OUT;
        float di = dinv[node];
        float acc = 0.f;
#pragma unroll
        for (int j = 0; j < F_HID; ++j) acc += B[node * F_HID + j] * w2s[j * F_OUT + c];
        out[i] = di * acc + b2s[c];
    }
}

extern "C" void kernel_launch(void* const* d_in, const int* in_sizes, int n_in,
                              void* d_out, int out_size, void* d_ws, size_t ws_size,
                              hipStream_t stream) {
    const float* x   = (const float*)d_in[0];
    const int*   idx = (const int*)d_in[1];     // int32 or int64 — runtime-detected
    const float* W1  = (const float*)d_in[2];
    const float* b1  = (const float*)d_in[3];
    const float* W2  = (const float*)d_in[4];
    const float* b2  = (const float*)d_in[5];
    float* out = (float*)d_out;

    const int n = in_sizes[0] / F_IN;       // 100000
    const int E = in_sizes[1] / 2;          // 6400000

    // workspace layout (bytes)
    char* ws = (char*)d_ws;
    int*   flag = (int*)ws;                          // 4 B
    float* dinv = (float*)(ws + 1024);               // n floats
    float* buf1 = (float*)(ws + 1024 + ((size_t)n * 4 + 255) / 256 * 256);
    float* buf2 = buf1 + (size_t)n * F_HID;

    const int B256 = 256;
    int nb_n   = (n + B256 - 1) / B256;
    int nb_nf  = (n * F_HID + B256 - 1) / B256;

    k_detect<<<1, B256, 0, stream>>>(idx, flag);
    k_deg_init<<<nb_n, B256, 0, stream>>>(dinv, n);
    k_deg_count<<<4096, B256, 0, stream>>>(idx, flag, dinv, E);
    k_rsqrt<<<nb_n, B256, 0, stream>>>(dinv, n);
    k_gemm1<<<(n + 15) / 16, B256, 0, stream>>>(x, W1, dinv, buf1, buf2, n);
    k_scatter<<<32768, B256, 0, stream>>>(idx, flag, buf1, buf2, E);   // layer 1 agg
    k_apply<<<nb_nf, B256, 0, stream>>>(b1, dinv, buf1, buf2, n);
    k_scatter<<<32768, B256, 0, stream>>>(idx, flag, buf1, buf2, E);   // layer 2 agg
    k_out<<<8192, B256, 0, stream>>>(buf2, dinv, W2, b2, out, n);
}